// Round 1
// baseline (175.151 us; speedup 1.0000x reference)
//
#include <hip/hip_runtime.h>
#include <hip/hip_bf16.h>

#define B_  16384
#define I_  512
#define H1_ 256
#define H2_ 128
#define E_  8
#define T_  2

typedef __attribute__((ext_vector_type(8))) short short8;
typedef __attribute__((ext_vector_type(4))) float float4_t;

__device__ inline unsigned short f2bf(float f) {
    union { float f; unsigned u; } v; v.f = f;
    unsigned r = v.u + 0x7FFFu + ((v.u >> 16) & 1u);
    return (unsigned short)(r >> 16);
}

// async global->LDS, 16B per lane. LDS dest = wave-uniform base + lane*16.
__device__ inline void async_copy16(const unsigned short* g, unsigned short* l) {
    __builtin_amdgcn_global_load_lds(
        (const __attribute__((address_space(1))) void*)g,
        (__attribute__((address_space(3))) void*)l,
        16, 0, 0);
}

// ================= prep + gates megakernel (one dispatch) =================
// UNCHANGED from verified kernel: x->bf16 (xb), W1^T (w1t), W2^T (w2t), gate softmax.
__global__ void prep_gates_kernel(const float* __restrict__ x,
                                  unsigned short* __restrict__ xb,
                                  const float* __restrict__ W1,
                                  unsigned short* __restrict__ w1t,
                                  const float* __restrict__ W2,
                                  unsigned short* __restrict__ w2t,
                                  const float* __restrict__ Wg,
                                  const float* __restrict__ bg,
                                  float* __restrict__ gates) {
    __shared__ __align__(16) char smem[16 * 520 * 2 + 4 * 16 * 16 * 4];  // 20.6 KB
    int bid = blockIdx.x;
    int t = threadIdx.x;

    if (bid < 1024) {
        unsigned short* wgtL = (unsigned short*)smem;          // [16][520] padded
        float (*red)[16][16] = (float (*)[16][16])(smem + 16 * 520 * 2);
#pragma unroll
        for (int j = 0; j < 32; ++j) {
            int idx = j * 256 + t;               // 0..8191
            int e = idx & 7, i = (idx >> 3) & 511, task = idx >> 12;
            wgtL[(task * 8 + e) * 520 + i] = f2bf(Wg[idx]);
        }
        __syncthreads();

        int w = t >> 6, lane = t & 63;
        int col = lane & 15, quad = lane >> 4;
        int b0 = bid * 16;
        int k0 = w * 128;
        const float* xr = x + (size_t)(b0 + col) * I_ + k0 + quad * 8;
        unsigned short* xw = xb + (size_t)(b0 + col) * I_ + k0 + quad * 8;
        const unsigned short* bL = &wgtL[col * 520 + k0 + quad * 8];
        float4_t acc = {0.f, 0.f, 0.f, 0.f};
#pragma unroll
        for (int ks = 0; ks < 128; ks += 32) {
            float4_t xa = *(const float4_t*)(xr + ks);
            float4_t xc = *(const float4_t*)(xr + ks + 4);
            short8 a;
            a[0] = (short)f2bf(xa[0]); a[1] = (short)f2bf(xa[1]);
            a[2] = (short)f2bf(xa[2]); a[3] = (short)f2bf(xa[3]);
            a[4] = (short)f2bf(xc[0]); a[5] = (short)f2bf(xc[1]);
            a[6] = (short)f2bf(xc[2]); a[7] = (short)f2bf(xc[3]);
            *(short8*)(xw + ks) = a;
            short8 b = *(const short8*)(bL + ks);
            acc = __builtin_amdgcn_mfma_f32_16x16x32_bf16(a, b, acc, 0, 0, 0);
        }
#pragma unroll
        for (int p = 0; p < 4; ++p)
            red[w][quad * 4 + p][col] = acc[p];
        __syncthreads();
        int r = t >> 4, te = t & 15;
        float v = red[0][r][te] + red[1][r][te] + red[2][r][te] + red[3][r][te] + bg[te];
        float m = v;
        m = fmaxf(m, __shfl_xor(m, 1));
        m = fmaxf(m, __shfl_xor(m, 2));
        m = fmaxf(m, __shfl_xor(m, 4));
        float ev = __expf(v - m);
        float s = ev;
        s += __shfl_xor(s, 1);
        s += __shfl_xor(s, 2);
        s += __shfl_xor(s, 4);
        gates[(size_t)te * B_ + b0 + r] = ev / s;
    } else {
        float (*tile)[33] = (float (*)[33])smem;
        const float* in; unsigned short* outp; int R, C, e, r0, c0;
        if (bid < 2048) {
            int tl = bid - 1024;               // 8 e x 16 rblk x 8 cblk
            e = tl >> 7; int rem = tl & 127;
            R = I_; C = H1_;
            r0 = (rem >> 3) * 32; c0 = (rem & 7) * 32;
            in = W1; outp = w1t;
        } else {
            int tl = bid - 2048;               // 8 e x 8 rblk x 4 cblk
            e = tl >> 5; int rem = tl & 31;
            R = H1_; C = H2_;
            r0 = (rem >> 2) * 32; c0 = (rem & 3) * 32;
            in = W2; outp = w2t;
        }
        const float* inp = in + (size_t)e * R * C;
        unsigned short* op = outp + (size_t)e * R * C;
        int tx = t & 31, ty = t >> 5;          // (32, 8)
#pragma unroll
        for (int j = 0; j < 32; j += 8)
            tile[ty + j][tx] = inp[(size_t)(r0 + ty + j) * C + c0 + tx];
        __syncthreads();
#pragma unroll
        for (int j = 0; j < 32; j += 8)
            op[(size_t)(c0 + ty + j) * R + r0 + tx] = f2bf(tile[tx][ty + j]);
    }
}

// ================= megafused: layer1 + layer2 + gated combine =================
// One block per CU: 64 batch rows, 512 threads (8 waves), LDS 112 KB.
// Per expert: 8 K-chunks layer-1 (A=x [64x64] 8KB + B=w1t [256x64] 32KB, dbuf,
// T3-minimum pipeline: issue next stage -> compute -> one barrier), epilogue
// writes h (bias+relu, bf16) into LDS Hs [64x256] swizzled; 4 K-chunks layer-2
// (B=w2t [128x64] 16KB) read Hs directly; towers accumulate in registers.
// h NEVER touches HBM. All LDS reads 8-slot XOR-swizzled; global_load_lds
// sources pre-swizzled (linear LDS dest).
__global__ __launch_bounds__(512, 2)
void megafused_kernel(const unsigned short* __restrict__ xb,
                      const unsigned short* __restrict__ w1t,
                      const unsigned short* __restrict__ w2t,
                      const float* __restrict__ b1,
                      const float* __restrict__ b2,
                      const float* __restrict__ gates,
                      float* __restrict__ out) {
    __shared__ __align__(16) unsigned short Ab[2][64 * 64];    // 16 KB  A chunks
    __shared__ __align__(16) unsigned short Bb[2][256 * 64];   // 64 KB  B chunks
    __shared__ __align__(16) unsigned short Hs[64 * 256];      // 32 KB  h slab

    int b0 = blockIdx.x * 64;
    int t = threadIdx.x, w = t >> 6, lane = t & 63;
    int col = lane & 15, quad = lane >> 4;
    int wm  = (w & 1) * 32;        // m-offset (both layers)
    int wn  = (w >> 1) * 64;       // layer-1 n-offset (N=256, 4 n-slices)
    int wn2 = (w >> 1) * 32;       // layer-2 n-offset (N=128, 4 n-slices)

    // staging geometry: one issue round = 512 lanes x 16 B = 64 rows x 64 k.
    // thread's row within a round; swizzled source k-slot (reader slot s of
    // row r holds global chunk s ^ (r&7); rows in later rounds keep r&7).
    int rA = w * 8 + (lane >> 3);                  // 0..63
    int cswz = ((lane & 7) ^ (rA & 7)) * 8;        // element offset in 64-k chunk

    const unsigned short* xsrc = xb + (size_t)(b0 + rA) * I_ + cswz;

    auto stage_l1 = [&](int bufn, int e, int sp) {
        async_copy16(xsrc + sp * 64, &Ab[bufn][w * 512]);
        const unsigned short* wp = w1t + (size_t)e * (H1_ * I_) +
                                   (size_t)rA * I_ + sp * 64 + cswz;
#pragma unroll
        for (int j = 0; j < 4; ++j)
            async_copy16(wp + (size_t)j * (64 * I_), &Bb[bufn][j * 4096 + w * 512]);
    };
    auto stage_l2 = [&](int bufn, int e, int kc) {
        const unsigned short* wp = w2t + (size_t)e * (H2_ * H1_) +
                                   (size_t)rA * H1_ + kc * 64 + cswz;
#pragma unroll
        for (int j = 0; j < 2; ++j)
            async_copy16(wp + (size_t)j * (64 * H1_), &Bb[bufn][j * 4096 + w * 512]);
    };

    float4_t tw[2][2][2];   // [task][mi][ni] tower accumulators
#pragma unroll
    for (int a = 0; a < 2; ++a)
#pragma unroll
        for (int mi = 0; mi < 2; ++mi)
#pragma unroll
            for (int ni = 0; ni < 2; ++ni)
                tw[a][mi][ni] = (float4_t){0.f, 0.f, 0.f, 0.f};

    // prologue: chunk (e=0, sp=0) -> buf 0
    stage_l1(0, 0, 0);
    __syncthreads();

#pragma unroll 1
    for (int e = 0; e < E_; ++e) {
        // -------- layer 1: 8 K-chunks of 64, dbuf (cur = sp&1) --------
        float4_t acc1[2][4];
#pragma unroll
        for (int mi = 0; mi < 2; ++mi)
#pragma unroll
            for (int ni = 0; ni < 4; ++ni)
                acc1[mi][ni] = (float4_t){0.f, 0.f, 0.f, 0.f};

#pragma unroll
        for (int sp = 0; sp < 8; ++sp) {
            int cur = sp & 1, nb = cur ^ 1;
            if (sp < 7) stage_l1(nb, e, sp + 1);
            else        stage_l2(nb, e, 0);
#pragma unroll
            for (int kk = 0; kk < 64; kk += 32) {
                int q = (kk >> 3) + quad;          // 0..7
                short8 af[2], bfv[4];
#pragma unroll
                for (int mi = 0; mi < 2; ++mi) {
                    int r = wm + mi * 16 + col;
                    af[mi] = *(const short8*)&Ab[cur][r * 64 + ((q ^ (r & 7)) << 3)];
                }
#pragma unroll
                for (int ni = 0; ni < 4; ++ni) {
                    int n = wn + ni * 16 + col;
                    bfv[ni] = *(const short8*)&Bb[cur][n * 64 + ((q ^ (n & 7)) << 3)];
                }
#pragma unroll
                for (int mi = 0; mi < 2; ++mi)
#pragma unroll
                    for (int ni = 0; ni < 4; ++ni)
                        acc1[mi][ni] = __builtin_amdgcn_mfma_f32_16x16x32_bf16(
                            af[mi], bfv[ni], acc1[mi][ni], 0, 0, 0);
            }
            if (sp == 7) {
                // layer-1 epilogue: bias + relu -> Hs (swizzled bf16)
#pragma unroll
                for (int ni = 0; ni < 4; ++ni) {
                    int n = wn + ni * 16 + col;
                    float bv = b1[e * H1_ + n];
                    int c = n >> 3, nl = n & 7;
#pragma unroll
                    for (int mi = 0; mi < 2; ++mi) {
#pragma unroll
                        for (int p = 0; p < 4; ++p) {
                            int r = wm + mi * 16 + quad * 4 + p;
                            float v = acc1[mi][ni][p] + bv;
                            v = v > 0.f ? v : 0.f;
                            Hs[r * 256 + (((c & 24) | ((c ^ r) & 7)) << 3) + nl] = f2bf(v);
                        }
                    }
                }
            }
            __syncthreads();
        }

        // gate loads (in flight under layer-2 compute)
        float g0v[2][4], g1v[2][4];
#pragma unroll
        for (int mi = 0; mi < 2; ++mi)
#pragma unroll
            for (int p = 0; p < 4; ++p) {
                int r = b0 + wm + mi * 16 + quad * 4 + p;
                g0v[mi][p] = gates[(size_t)e * B_ + r];
                g1v[mi][p] = gates[(size_t)(8 + e) * B_ + r];
            }

        // -------- layer 2: 4 K-chunks of 64 (A = Hs resident) --------
        float4_t acc2[2][2];
#pragma unroll
        for (int mi = 0; mi < 2; ++mi)
#pragma unroll
            for (int ni = 0; ni < 2; ++ni)
                acc2[mi][ni] = (float4_t){0.f, 0.f, 0.f, 0.f};

#pragma unroll
        for (int kc = 0; kc < 4; ++kc) {
            int cur = kc & 1, nb = cur ^ 1;
            if (kc < 3)     stage_l2(nb, e, kc + 1);
            else if (e < 7) stage_l1(nb, e + 1, 0);
#pragma unroll
            for (int kk = 0; kk < 64; kk += 32) {
                int q = (kk >> 3) + quad;          // 0..7
                int cH = kc * 8 + q;               // 0..31
                short8 af[2], bfv[2];
#pragma unroll
                for (int mi = 0; mi < 2; ++mi) {
                    int r = wm + mi * 16 + col;
                    af[mi] = *(const short8*)&Hs[r * 256 + (((cH & 24) | ((cH ^ r) & 7)) << 3)];
                }
#pragma unroll
                for (int ni = 0; ni < 2; ++ni) {
                    int n = wn2 + ni * 16 + col;
                    bfv[ni] = *(const short8*)&Bb[cur][n * 64 + ((q ^ (n & 7)) << 3)];
                }
#pragma unroll
                for (int mi = 0; mi < 2; ++mi)
#pragma unroll
                    for (int ni = 0; ni < 2; ++ni)
                        acc2[mi][ni] = __builtin_amdgcn_mfma_f32_16x16x32_bf16(
                            af[mi], bfv[ni], acc2[mi][ni], 0, 0, 0);
            }
            __syncthreads();
        }

        // -------- combine epilogue: towers += gate * relu(acc2 + b2) --------
        float bv2[2];
#pragma unroll
        for (int ni = 0; ni < 2; ++ni)
            bv2[ni] = b2[e * H2_ + wn2 + ni * 16 + col];
#pragma unroll
        for (int mi = 0; mi < 2; ++mi) {
#pragma unroll
            for (int p = 0; p < 4; ++p) {
#pragma unroll
                for (int ni = 0; ni < 2; ++ni) {
                    float v = acc2[mi][ni][p] + bv2[ni];
                    v = v > 0.f ? v : 0.f;
                    tw[0][mi][ni][p] += g0v[mi][p] * v;
                    tw[1][mi][ni][p] += g1v[mi][p] * v;
                }
            }
        }
    }

    // -------- store towers [T][B][H2] --------
#pragma unroll
    for (int mi = 0; mi < 2; ++mi) {
#pragma unroll
        for (int ni = 0; ni < 2; ++ni) {
            int n = wn2 + ni * 16 + col;
#pragma unroll
            for (int p = 0; p < 4; ++p) {
                size_t r = (size_t)(b0 + wm + mi * 16 + quad * 4 + p);
                out[r * H2_ + n] = tw[0][mi][ni][p];
                out[(size_t)B_ * H2_ + r * H2_ + n] = tw[1][mi][ni][p];
            }
        }
    }
}

extern "C" void kernel_launch(void* const* d_in, const int* in_sizes, int n_in,
                              void* d_out, int out_size, void* d_ws, size_t ws_size,
                              hipStream_t stream) {
    const float* x  = (const float*)d_in[0];
    const float* W1 = (const float*)d_in[1];
    const float* b1 = (const float*)d_in[2];
    const float* W2 = (const float*)d_in[3];
    const float* b2 = (const float*)d_in[4];
    const float* Wg = (const float*)d_in[5];
    const float* bg = (const float*)d_in[6];
    float* out = (float*)d_out;

    char* ws = (char*)d_ws;
    unsigned short* xb    = (unsigned short*)(ws);                // 16,777,216 B
    unsigned short* w1t   = (unsigned short*)(ws + 16777216);     //  2,097,152 B
    unsigned short* w2t   = (unsigned short*)(ws + 18874368);     //    524,288 B
    float*          gates = (float*)(ws + 19398656);              //  1,048,576 B  [16][B]
    // total: 20,447,232 B (h eliminated)

    // dispatch 1: all prep + gates (x->bf16, W1^T, W2^T, gate softmax)
    prep_gates_kernel<<<dim3(2304), 256, 0, stream>>>(x, xb, W1, w1t, W2, w2t, Wg, bg, gates);

    // dispatch 2: fused layer1 + layer2 + gated combine (h stays in LDS)
    megafused_kernel<<<dim3(B_ / 64), 512, 0, stream>>>(xb, w1t, w2t, b1, b2, gates, out);
}

// Round 2
// 168.225 us; speedup vs baseline: 1.0412x; 1.0412x over previous
//
#include <hip/hip_runtime.h>
#include <hip/hip_bf16.h>

#define B_  16384
#define I_  512
#define H1_ 256
#define H2_ 128
#define E_  8
#define T_  2

typedef __attribute__((ext_vector_type(8))) short short8;
typedef __attribute__((ext_vector_type(4))) float float4_t;

__device__ inline unsigned short f2bf(float f) {
    union { float f; unsigned u; } v; v.f = f;
    unsigned r = v.u + 0x7FFFu + ((v.u >> 16) & 1u);
    return (unsigned short)(r >> 16);
}

// async global->LDS, 16B per lane. LDS dest = wave-uniform base + lane*16.
__device__ inline void async_copy16(const unsigned short* g, unsigned short* l) {
    __builtin_amdgcn_global_load_lds(
        (const __attribute__((address_space(1))) void*)g,
        (__attribute__((address_space(3))) void*)l,
        16, 0, 0);
}

// ================= prep + gates megakernel (one dispatch) =================
// UNCHANGED (verified): x->bf16 (xb), W1^T (w1t), W2^T (w2t), gate softmax.
__global__ void prep_gates_kernel(const float* __restrict__ x,
                                  unsigned short* __restrict__ xb,
                                  const float* __restrict__ W1,
                                  unsigned short* __restrict__ w1t,
                                  const float* __restrict__ W2,
                                  unsigned short* __restrict__ w2t,
                                  const float* __restrict__ Wg,
                                  const float* __restrict__ bg,
                                  float* __restrict__ gates) {
    __shared__ __align__(16) char smem[16 * 520 * 2 + 4 * 16 * 16 * 4];  // 20.6 KB
    int bid = blockIdx.x;
    int t = threadIdx.x;

    if (bid < 1024) {
        unsigned short* wgtL = (unsigned short*)smem;          // [16][520] padded
        float (*red)[16][16] = (float (*)[16][16])(smem + 16 * 520 * 2);
#pragma unroll
        for (int j = 0; j < 32; ++j) {
            int idx = j * 256 + t;               // 0..8191
            int e = idx & 7, i = (idx >> 3) & 511, task = idx >> 12;
            wgtL[(task * 8 + e) * 520 + i] = f2bf(Wg[idx]);
        }
        __syncthreads();

        int w = t >> 6, lane = t & 63;
        int col = lane & 15, quad = lane >> 4;
        int b0 = bid * 16;
        int k0 = w * 128;
        const float* xr = x + (size_t)(b0 + col) * I_ + k0 + quad * 8;
        unsigned short* xw = xb + (size_t)(b0 + col) * I_ + k0 + quad * 8;
        const unsigned short* bL = &wgtL[col * 520 + k0 + quad * 8];
        float4_t acc = {0.f, 0.f, 0.f, 0.f};
#pragma unroll
        for (int ks = 0; ks < 128; ks += 32) {
            float4_t xa = *(const float4_t*)(xr + ks);
            float4_t xc = *(const float4_t*)(xr + ks + 4);
            short8 a;
            a[0] = (short)f2bf(xa[0]); a[1] = (short)f2bf(xa[1]);
            a[2] = (short)f2bf(xa[2]); a[3] = (short)f2bf(xa[3]);
            a[4] = (short)f2bf(xc[0]); a[5] = (short)f2bf(xc[1]);
            a[6] = (short)f2bf(xc[2]); a[7] = (short)f2bf(xc[3]);
            *(short8*)(xw + ks) = a;
            short8 b = *(const short8*)(bL + ks);
            acc = __builtin_amdgcn_mfma_f32_16x16x32_bf16(a, b, acc, 0, 0, 0);
        }
#pragma unroll
        for (int p = 0; p < 4; ++p)
            red[w][quad * 4 + p][col] = acc[p];
        __syncthreads();
        int r = t >> 4, te = t & 15;
        float v = red[0][r][te] + red[1][r][te] + red[2][r][te] + red[3][r][te] + bg[te];
        float m = v;
        m = fmaxf(m, __shfl_xor(m, 1));
        m = fmaxf(m, __shfl_xor(m, 2));
        m = fmaxf(m, __shfl_xor(m, 4));
        float ev = __expf(v - m);
        float s = ev;
        s += __shfl_xor(s, 1);
        s += __shfl_xor(s, 2);
        s += __shfl_xor(s, 4);
        gates[(size_t)te * B_ + b0 + r] = ev / s;
    } else {
        float (*tile)[33] = (float (*)[33])smem;
        const float* in; unsigned short* outp; int R, C, e, r0, c0;
        if (bid < 2048) {
            int tl = bid - 1024;               // 8 e x 16 rblk x 8 cblk
            e = tl >> 7; int rem = tl & 127;
            R = I_; C = H1_;
            r0 = (rem >> 3) * 32; c0 = (rem & 7) * 32;
            in = W1; outp = w1t;
        } else {
            int tl = bid - 2048;               // 8 e x 8 rblk x 4 cblk
            e = tl >> 5; int rem = tl & 31;
            R = H1_; C = H2_;
            r0 = (rem >> 2) * 32; c0 = (rem & 3) * 32;
            in = W2; outp = w2t;
        }
        const float* inp = in + (size_t)e * R * C;
        unsigned short* op = outp + (size_t)e * R * C;
        int tx = t & 31, ty = t >> 5;          // (32, 8)
#pragma unroll
        for (int j = 0; j < 32; j += 8)
            tile[ty + j][tx] = inp[(size_t)(r0 + ty + j) * C + c0 + tx];
        __syncthreads();
#pragma unroll
        for (int j = 0; j < 32; j += 8)
            op[(size_t)(c0 + ty + j) * R + r0 + tx] = f2bf(tile[tx][ty + j]);
    }
}

// ================= layer-1 GEMM: 256x256 tile, 4-phase counted-vmcnt pipeline =================
// h[e] = relu(xb * w1t[e]^T + b1[e]) in bf16.  M=B, N=H1=256 (one tile), K=I=512.
// 512 threads = 8 waves (2M x 4N); per-wave output 128x64 (8 m-frags x 4 n-frags).
// LDS 128 KB: A dbuf 2x32KB + B dbuf 2x32KB. Per K-step (BK=64): 4 phases, each
// {issue 2 prefetch loads for kt+1 | ds_read af subtile | 16 MFMA in setprio(1)}.
// Counted s_waitcnt vmcnt(2) once per K-step (prefetch spans barriers; drain-0
// only at the last step).  8-slot XOR swizzle on rows (pre-swizzled sources).
__global__ __launch_bounds__(512, 2)
void l1_gemm_kernel(const unsigned short* __restrict__ xb,
                    const unsigned short* __restrict__ w1t,
                    const float* __restrict__ b1,
                    unsigned short* __restrict__ h) {
    __shared__ __align__(16) unsigned short smem[65536];   // 128 KB

    // XCD-bijective swizzle (512 = 8*64): each XCD gets 8 m-tiles x all 8 experts
    int bid = blockIdx.x;
    int wg = (bid & 7) * 64 + (bid >> 3);
    int m0 = (wg >> 3) * 256;
    int e  = wg & 7;

    int t = threadIdx.x, w = t >> 6, lane = t & 63;
    int col = lane & 15, quad = lane >> 4;
    int wm = (w & 1) * 128;        // wave's M offset (8 frags of 16)
    int wn = (w >> 1) * 64;        // wave's N offset (4 frags of 16)

    // staging: per K-step, 4 issue groups (p) each 64 rows; thread row + swizzled k-chunk
    int rowA = w * 8 + (lane >> 3);                  // 0..63 (== t>>3)
    int csw  = ((lane & 7) ^ (rowA & 7)) * 8;        // pre-swizzled source chunk
    const unsigned short* aG = xb  + (size_t)(m0 + rowA) * I_ + csw;
    const unsigned short* bG = w1t + ((size_t)e * H1_ + rowA) * I_ + csw;

    unsigned short* AsBase = smem;            // + buf*16384 (32 KB per buf)
    unsigned short* BsBase = smem + 32768;    // + buf*16384
    int ldsw = w * 512;                       // wave chunk within an issue group

    float4_t acc[8][4];
#pragma unroll
    for (int mf = 0; mf < 8; ++mf)
#pragma unroll
        for (int nf = 0; nf < 4; ++nf)
            acc[mf][nf] = (float4_t){0.f, 0.f, 0.f, 0.f};

    // prologue: stage kt=0 into buf 0 (8 loads/thread)
#pragma unroll
    for (int p = 0; p < 4; ++p) {
        async_copy16(aG + ((size_t)p * 64) * I_, AsBase + p * 4096 + ldsw);
        async_copy16(bG + ((size_t)p * 64) * I_, BsBase + p * 4096 + ldsw);
    }

    short8 bf[4][2];   // B fragments held across all 4 phases of a K-step

#pragma unroll 1
    for (int kt = 0; kt < 8; ++kt) {
        const int cur = kt & 1, nb = cur ^ 1;
        unsigned short* Ac = AsBase + cur * 16384;
        unsigned short* Bc = BsBase + cur * 16384;
        unsigned short* An = AsBase + nb * 16384;
        unsigned short* Bn = BsBase + nb * 16384;
        const unsigned short* aN = aG + (size_t)(kt + 1) * 64;
        const unsigned short* bN = bG + (size_t)(kt + 1) * 64;

        // ---- K-step head: issue first prefetch pair, counted wait, barrier ----
        if (kt < 7) {
            async_copy16(aN, An + ldsw);
            async_copy16(bN, Bn + ldsw);
            asm volatile("s_waitcnt vmcnt(2)" ::: "memory");   // kt's 8 landed; 2 newer in flight
        } else {
            asm volatile("s_waitcnt vmcnt(0)" ::: "memory");   // final drain
        }
        asm volatile("s_barrier" ::: "memory");

        // B fragments for the whole K-step (8 x ds_read_b128)
#pragma unroll
        for (int nf = 0; nf < 4; ++nf) {
            int n = wn + nf * 16 + col;
#pragma unroll
            for (int kq = 0; kq < 2; ++kq) {
                int q = kq * 4 + quad;
                bf[nf][kq] = *(const short8*)&Bc[n * 64 + ((q ^ (n & 7)) << 3)];
            }
        }

        // ---- 4 phases: {prefetch pair | af reads | 16 MFMA} ----
#pragma unroll
        for (int p = 0; p < 4; ++p) {
            if (p > 0 && kt < 7) {
                async_copy16(aN + ((size_t)p * 64) * I_, An + p * 4096 + ldsw);
                async_copy16(bN + ((size_t)p * 64) * I_, Bn + p * 4096 + ldsw);
            }
            short8 af[2][2];
#pragma unroll
            for (int s = 0; s < 2; ++s) {
                int r = wm + (p * 2 + s) * 16 + col;
#pragma unroll
                for (int kq = 0; kq < 2; ++kq) {
                    int q = kq * 4 + quad;
                    af[s][kq] = *(const short8*)&Ac[r * 64 + ((q ^ (r & 7)) << 3)];
                }
            }
            asm volatile("s_waitcnt lgkmcnt(0)" ::: "memory");
            __builtin_amdgcn_sched_barrier(0);
            __builtin_amdgcn_s_setprio(1);
#pragma unroll
            for (int s = 0; s < 2; ++s)
#pragma unroll
                for (int nf = 0; nf < 4; ++nf)
#pragma unroll
                    for (int kq = 0; kq < 2; ++kq)
                        acc[p * 2 + s][nf] = __builtin_amdgcn_mfma_f32_16x16x32_bf16(
                            af[s][kq], bf[nf][kq], acc[p * 2 + s][nf], 0, 0, 0);
            __builtin_amdgcn_s_setprio(0);
            asm volatile("s_barrier" ::: "memory");
        }
    }

    // ---- epilogue: bias + relu -> bf16, LDS-restaged coalesced stores ----
    unsigned short* Ct = smem;                 // [128][stride 264] per half
    const float* bE = b1 + e * H1_;
#pragma unroll
    for (int half = 0; half < 2; ++half) {
        if ((w & 1) == half) {
#pragma unroll
            for (int mf = 0; mf < 8; ++mf) {
#pragma unroll
                for (int nf = 0; nf < 4; ++nf) {
                    int n = wn + nf * 16 + col;
                    float bv = bE[n];
#pragma unroll
                    for (int p2 = 0; p2 < 4; ++p2) {
                        float v = acc[mf][nf][p2] + bv;
                        v = v > 0.f ? v : 0.f;
                        Ct[(mf * 16 + quad * 4 + p2) * 264 + n] = f2bf(v);
                    }
                }
            }
        }
        __syncthreads();
        unsigned short* hrow = h + ((size_t)e * B_ + m0 + half * 128) * H1_;
#pragma unroll
        for (int j = 0; j < 8; ++j) {
            int idx = j * 512 + t;
            int row = idx >> 5, cc = idx & 31;
            short8 vv = *(const short8*)&Ct[row * 264 + cc * 8];
            *(short8*)&hrow[(size_t)row * H1_ + cc * 8] = vv;
        }
        __syncthreads();
    }
}

// ---------------- fused layer2 + gated combine, full H2 per block ----------------
// 64 rows x 128 cols (full H2) per block, grid B/64 = 256, 512 threads (8 waves).
// h read ONCE (67 MB vs 134 MB before).  LDS 100 KB: h slab 32K + w2 slab 64K + gates 4K.
__global__ __launch_bounds__(512, 2)
void fused_l2_combine_kernel(const unsigned short* __restrict__ h,
                             const unsigned short* __restrict__ w2t,
                             const float* __restrict__ b2,
                             const float* __restrict__ gates,
                             float* __restrict__ out) {
    __shared__ unsigned short As[64 * 256];    // 32 KB: h slab (64 rows x K=256)
    __shared__ unsigned short Bs[128 * 256];   // 64 KB: W2t (128 n x K=256)
    __shared__ float gL[16][64];               //  4 KB

    int b0 = blockIdx.x * 64;
    int t = threadIdx.x, w = t >> 6, lane = t & 63;
    int col = lane & 15, quad = lane >> 4;
    int wm = (w & 1) * 32, wn = (w >> 1) * 32;   // wn in {0,32,64,96}

    if (t < 256) {   // stage gates (first read after e=0's barrier)
        int te = t >> 4, r4 = (t & 15) * 4;
        *(float4_t*)&gL[te][r4] = *(const float4_t*)&gates[(size_t)te * B_ + b0 + r4];
    }

    float4_t tw0[2][2], tw1[2][2];
#pragma unroll
    for (int mi = 0; mi < 2; ++mi)
#pragma unroll
        for (int ni = 0; ni < 2; ++ni) {
            tw0[mi][ni] = (float4_t){0.f, 0.f, 0.f, 0.f};
            tw1[mi][ni] = (float4_t){0.f, 0.f, 0.f, 0.f};
        }

    int rL = w * 2 + (lane >> 5);       // row offset within a 16-row issue group
    int cL = lane & 31;                  // lds 16B-chunk index within row

    for (int e = 0; e < E_; ++e) {
        const unsigned short* hE  = h   + ((size_t)e * B_ + b0) * H1_;
        const unsigned short* w2E = w2t + (size_t)e * H2_ * H1_;

#pragma unroll
        for (int j = 0; j < 4; ++j) {           // h: 64 rows
            int r = j * 16 + rL;
            int cg = (cL & 24) | ((cL ^ r) & 7);
            async_copy16(hE + (size_t)r * H1_ + cg * 8, As + j * 4096 + w * 512);
        }
#pragma unroll
        for (int j = 0; j < 8; ++j) {           // w2t: 128 n-rows
            int r = j * 16 + rL;
            int cg = (cL & 24) | ((cL ^ r) & 7);
            async_copy16(w2E + (size_t)r * H1_ + cg * 8, Bs + j * 4096 + w * 512);
        }
        __syncthreads();

        float4_t acc[2][2];
#pragma unroll
        for (int mi = 0; mi < 2; ++mi)
#pragma unroll
            for (int ni = 0; ni < 2; ++ni)
                acc[mi][ni] = (float4_t){0.f, 0.f, 0.f, 0.f};

#pragma unroll
        for (int kk = 0; kk < 8; ++kk) {
            int c = kk * 4 + quad;               // 16B-chunk index in K
            short8 af[2], bfv[2];
#pragma unroll
            for (int mi = 0; mi < 2; ++mi) {
                int r = wm + mi * 16 + col;
                int l = (c & 24) | ((c ^ r) & 7);
                af[mi] = *(const short8*)&As[r * 256 + l * 8];
            }
#pragma unroll
            for (int ni = 0; ni < 2; ++ni) {
                int n = wn + ni * 16 + col;
                int l = (c & 24) | ((c ^ n) & 7);
                bfv[ni] = *(const short8*)&Bs[n * 256 + l * 8];
            }
#pragma unroll
            for (int mi = 0; mi < 2; ++mi)
#pragma unroll
                for (int ni = 0; ni < 2; ++ni)
                    acc[mi][ni] = __builtin_amdgcn_mfma_f32_16x16x32_bf16(
                        af[mi], bfv[ni], acc[mi][ni], 0, 0, 0);
        }
        __syncthreads();

        // bias + relu + gated accumulate
#pragma unroll
        for (int ni = 0; ni < 2; ++ni) {
            float bv = b2[e * H2_ + wn + ni * 16 + col];
#pragma unroll
            for (int mi = 0; mi < 2; ++mi) {
#pragma unroll
                for (int p = 0; p < 4; ++p) {
                    int rloc = wm + mi * 16 + quad * 4 + p;
                    float v = acc[mi][ni][p] + bv;
                    v = v > 0.f ? v : 0.f;
                    tw0[mi][ni][p] += gL[e][rloc] * v;
                    tw1[mi][ni][p] += gL[8 + e][rloc] * v;
                }
            }
        }
    }

    // write out [T][B][H2]
#pragma unroll
    for (int mi = 0; mi < 2; ++mi) {
#pragma unroll
        for (int ni = 0; ni < 2; ++ni) {
            int n = wn + ni * 16 + col;
#pragma unroll
            for (int p = 0; p < 4; ++p) {
                int r = b0 + wm + mi * 16 + quad * 4 + p;
                out[(size_t)r * H2_ + n] = tw0[mi][ni][p];
                out[(size_t)B_ * H2_ + (size_t)r * H2_ + n] = tw1[mi][ni][p];
            }
        }
    }
}

extern "C" void kernel_launch(void* const* d_in, const int* in_sizes, int n_in,
                              void* d_out, int out_size, void* d_ws, size_t ws_size,
                              hipStream_t stream) {
    const float* x  = (const float*)d_in[0];
    const float* W1 = (const float*)d_in[1];
    const float* b1 = (const float*)d_in[2];
    const float* W2 = (const float*)d_in[3];
    const float* b2 = (const float*)d_in[4];
    const float* Wg = (const float*)d_in[5];
    const float* bg = (const float*)d_in[6];
    float* out = (float*)d_out;

    char* ws = (char*)d_ws;
    unsigned short* xb    = (unsigned short*)(ws);                // 16,777,216 B
    unsigned short* w1t   = (unsigned short*)(ws + 16777216);     //  2,097,152 B
    unsigned short* w2t   = (unsigned short*)(ws + 18874368);     //    524,288 B
    float*          gates = (float*)(ws + 19398656);              //  1,048,576 B  [16][B]
    unsigned short* h     = (unsigned short*)(ws + 20447232);     // 67,108,864 B
    // total: 87,556,096 B

    // dispatch 1: all prep + gates (x->bf16, W1^T, W2^T, gate softmax)
    prep_gates_kernel<<<dim3(2304), 256, 0, stream>>>(x, xb, W1, w1t, W2, w2t, Wg, bg, gates);

    // dispatch 2: layer 1 grouped GEMM, 256^2 tile, counted-vmcnt pipeline
    l1_gemm_kernel<<<dim3(512), 512, 0, stream>>>(xb, w1t, b1, h);

    // dispatch 3: fused layer 2 + gated combine (h read once)
    fused_l2_combine_kernel<<<dim3(B_ / 64), 512, 0, stream>>>(h, w2t, b2, gates, out);
}

// Round 4
// 163.591 us; speedup vs baseline: 1.0707x; 1.0283x over previous
//
#include <hip/hip_runtime.h>
#include <hip/hip_bf16.h>

#define B_  16384
#define I_  512
#define H1_ 256
#define H2_ 128
#define E_  8
#define T_  2

typedef __attribute__((ext_vector_type(8))) short short8;
typedef __attribute__((ext_vector_type(4))) float float4_t;

__device__ inline unsigned short f2bf(float f) {
    union { float f; unsigned u; } v; v.f = f;
    unsigned r = v.u + 0x7FFFu + ((v.u >> 16) & 1u);
    return (unsigned short)(r >> 16);
}

// async global->LDS, 16B per lane. LDS dest = wave-uniform base + lane*16.
__device__ inline void async_copy16(const unsigned short* g, unsigned short* l) {
    __builtin_amdgcn_global_load_lds(
        (const __attribute__((address_space(1))) void*)g,
        (__attribute__((address_space(3))) void*)l,
        16, 0, 0);
}

// ================= prep + gates megakernel (one dispatch) =================
// UNCHANGED (verified): x->bf16 (xb), W1^T (w1t), W2^T (w2t), gate softmax.
__global__ void prep_gates_kernel(const float* __restrict__ x,
                                  unsigned short* __restrict__ xb,
                                  const float* __restrict__ W1,
                                  unsigned short* __restrict__ w1t,
                                  const float* __restrict__ W2,
                                  unsigned short* __restrict__ w2t,
                                  const float* __restrict__ Wg,
                                  const float* __restrict__ bg,
                                  float* __restrict__ gates) {
    __shared__ __align__(16) char smem[16 * 520 * 2 + 4 * 16 * 16 * 4];  // 20.6 KB
    int bid = blockIdx.x;
    int t = threadIdx.x;

    if (bid < 1024) {
        unsigned short* wgtL = (unsigned short*)smem;          // [16][520] padded
        float (*red)[16][16] = (float (*)[16][16])(smem + 16 * 520 * 2);
#pragma unroll
        for (int j = 0; j < 32; ++j) {
            int idx = j * 256 + t;               // 0..8191
            int e = idx & 7, i = (idx >> 3) & 511, task = idx >> 12;
            wgtL[(task * 8 + e) * 520 + i] = f2bf(Wg[idx]);
        }
        __syncthreads();

        int w = t >> 6, lane = t & 63;
        int col = lane & 15, quad = lane >> 4;
        int b0 = bid * 16;
        int k0 = w * 128;
        const float* xr = x + (size_t)(b0 + col) * I_ + k0 + quad * 8;
        unsigned short* xw = xb + (size_t)(b0 + col) * I_ + k0 + quad * 8;
        const unsigned short* bL = &wgtL[col * 520 + k0 + quad * 8];
        float4_t acc = {0.f, 0.f, 0.f, 0.f};
#pragma unroll
        for (int ks = 0; ks < 128; ks += 32) {
            float4_t xa = *(const float4_t*)(xr + ks);
            float4_t xc = *(const float4_t*)(xr + ks + 4);
            short8 a;
            a[0] = (short)f2bf(xa[0]); a[1] = (short)f2bf(xa[1]);
            a[2] = (short)f2bf(xa[2]); a[3] = (short)f2bf(xa[3]);
            a[4] = (short)f2bf(xc[0]); a[5] = (short)f2bf(xc[1]);
            a[6] = (short)f2bf(xc[2]); a[7] = (short)f2bf(xc[3]);
            *(short8*)(xw + ks) = a;
            short8 b = *(const short8*)(bL + ks);
            acc = __builtin_amdgcn_mfma_f32_16x16x32_bf16(a, b, acc, 0, 0, 0);
        }
#pragma unroll
        for (int p = 0; p < 4; ++p)
            red[w][quad * 4 + p][col] = acc[p];
        __syncthreads();
        int r = t >> 4, te = t & 15;
        float v = red[0][r][te] + red[1][r][te] + red[2][r][te] + red[3][r][te] + bg[te];
        float m = v;
        m = fmaxf(m, __shfl_xor(m, 1));
        m = fmaxf(m, __shfl_xor(m, 2));
        m = fmaxf(m, __shfl_xor(m, 4));
        float ev = __expf(v - m);
        float s = ev;
        s += __shfl_xor(s, 1);
        s += __shfl_xor(s, 2);
        s += __shfl_xor(s, 4);
        gates[(size_t)te * B_ + b0 + r] = ev / s;
    } else {
        float (*tile)[33] = (float (*)[33])smem;
        const float* in; unsigned short* outp; int R, C, e, r0, c0;
        if (bid < 2048) {
            int tl = bid - 1024;               // 8 e x 16 rblk x 8 cblk
            e = tl >> 7; int rem = tl & 127;
            R = I_; C = H1_;
            r0 = (rem >> 3) * 32; c0 = (rem & 7) * 32;
            in = W1; outp = w1t;
        } else {
            int tl = bid - 2048;               // 8 e x 8 rblk x 4 cblk
            e = tl >> 5; int rem = tl & 31;
            R = H1_; C = H2_;
            r0 = (rem >> 2) * 32; c0 = (rem & 3) * 32;
            in = W2; outp = w2t;
        }
        const float* inp = in + (size_t)e * R * C;
        unsigned short* op = outp + (size_t)e * R * C;
        int tx = t & 31, ty = t >> 5;          // (32, 8)
#pragma unroll
        for (int j = 0; j < 32; j += 8)
            tile[ty + j][tx] = inp[(size_t)(r0 + ty + j) * C + c0 + tx];
        __syncthreads();
#pragma unroll
        for (int j = 0; j < 32; j += 8)
            op[(size_t)(c0 + ty + j) * R + r0 + tx] = f2bf(tile[tx][ty + j]);
    }
}

// ================= layer-1 GEMM: 256x256 tile, issue-at-head counted-vmcnt pipeline =================
// UNCHANGED from round 3 (race-free: trailing barrier of kt-1 orders that
// buffer's reads before kt's overwrite-issue; head vmcnt+barrier orders
// arrival before reads; fragment/swizzle indexing identical to verified r2).
__global__ __launch_bounds__(512, 2)
void l1_gemm_kernel(const unsigned short* __restrict__ xb,
                    const unsigned short* __restrict__ w1t,
                    const float* __restrict__ b1,
                    unsigned short* __restrict__ h) {
    __shared__ __align__(16) unsigned short smem[65536];   // 128 KB

    // XCD-bijective swizzle (512 = 8*64): XCD k gets m-tiles 8k..8k+7 x all experts
    int bid = blockIdx.x;
    int wg = (bid & 7) * 64 + (bid >> 3);
    int m0 = (wg >> 3) * 256;
    int e  = wg & 7;

    int t = threadIdx.x, w = t >> 6, lane = t & 63;
    int col = lane & 15, quad = lane >> 4;
    int wm = (w & 1) * 128;        // wave's M offset (8 frags of 16)
    int wn = (w >> 1) * 64;        // wave's N offset (4 frags of 16)

    int rowA = t >> 3;                               // 0..63
    int csw  = ((t & 7) ^ (rowA & 7)) * 8;           // pre-swizzled source chunk
    const unsigned short* aG = xb  + (size_t)(m0 + rowA) * I_ + csw;
    const unsigned short* bG = w1t + ((size_t)e * H1_ + rowA) * I_ + csw;

    unsigned short* As = smem;                // [2][16384]
    unsigned short* Bs = smem + 32768;        // [2][16384]
    int ldsw = w * 512;                       // wave chunk within an issue group

    float4_t acc[8][4];
#pragma unroll
    for (int mf = 0; mf < 8; ++mf)
#pragma unroll
        for (int nf = 0; nf < 4; ++nf)
            acc[mf][nf] = (float4_t){0.f, 0.f, 0.f, 0.f};

    // prologue: stage kt=0 into buf 0 (8 loads/thread)
#pragma unroll
    for (int p = 0; p < 4; ++p) {
        async_copy16(aG + ((size_t)p * 64) * I_, As + p * 4096 + ldsw);
        async_copy16(bG + ((size_t)p * 64) * I_, Bs + p * 4096 + ldsw);
    }

#pragma unroll 1
    for (int kt = 0; kt < 8; ++kt) {
        const int cur = kt & 1;
        const unsigned short* Ac = As + cur * 16384;
        const unsigned short* Bc = Bs + cur * 16384;

        if (kt < 7) {
            unsigned short* An = As + (cur ^ 1) * 16384;
            unsigned short* Bn = Bs + (cur ^ 1) * 16384;
            const unsigned short* aN = aG + (size_t)(kt + 1) * 64;
            const unsigned short* bN = bG + (size_t)(kt + 1) * 64;
#pragma unroll
            for (int p = 0; p < 4; ++p) {
                async_copy16(aN + ((size_t)p * 64) * I_, An + p * 4096 + ldsw);
                async_copy16(bN + ((size_t)p * 64) * I_, Bn + p * 4096 + ldsw);
            }
            asm volatile("s_waitcnt vmcnt(8)" ::: "memory");  // kt's 8 landed; kt+1's 8 in flight
        } else {
            asm volatile("s_waitcnt vmcnt(0)" ::: "memory");  // final drain
        }
        asm volatile("s_barrier" ::: "memory");               // all waves' kt data visible

        // whole K-step compute: 2 halves of K, 12 ds_read + 32 MFMA each
#pragma unroll
        for (int kq = 0; kq < 2; ++kq) {
            int q = kq * 4 + quad;          // 0..7
            short8 af[8], bfv[4];
#pragma unroll
            for (int mf = 0; mf < 8; ++mf) {
                int r = wm + mf * 16 + col;
                af[mf] = *(const short8*)&Ac[r * 64 + ((q ^ (r & 7)) << 3)];
            }
#pragma unroll
            for (int nf = 0; nf < 4; ++nf) {
                int n = wn + nf * 16 + col;
                bfv[nf] = *(const short8*)&Bc[n * 64 + ((q ^ (n & 7)) << 3)];
            }
            __builtin_amdgcn_s_setprio(1);
#pragma unroll
            for (int mf = 0; mf < 8; ++mf)
#pragma unroll
                for (int nf = 0; nf < 4; ++nf)
                    acc[mf][nf] = __builtin_amdgcn_mfma_f32_16x16x32_bf16(
                        af[mf], bfv[nf], acc[mf][nf], 0, 0, 0);
            __builtin_amdgcn_s_setprio(0);
        }
        asm volatile("s_barrier" ::: "memory");               // reads done -> buffer reusable
    }

    // ---- epilogue: bias + relu -> bf16, LDS-restaged coalesced stores ----
    unsigned short* Ct = smem;                 // [128][stride 264] per half
    const float* bE = b1 + e * H1_;
#pragma unroll
    for (int half = 0; half < 2; ++half) {
        if ((w & 1) == half) {
#pragma unroll
            for (int mf = 0; mf < 8; ++mf) {
#pragma unroll
                for (int nf = 0; nf < 4; ++nf) {
                    int n = wn + nf * 16 + col;
                    float bv = bE[n];
#pragma unroll
                    for (int p2 = 0; p2 < 4; ++p2) {
                        float v = acc[mf][nf][p2] + bv;
                        v = v > 0.f ? v : 0.f;
                        Ct[(mf * 16 + quad * 4 + p2) * 264 + n] = f2bf(v);
                    }
                }
            }
        }
        __syncthreads();
        unsigned short* hrow = h + ((size_t)e * B_ + m0 + half * 128) * H1_;
#pragma unroll
        for (int j = 0; j < 8; ++j) {
            int idx = j * 512 + t;
            int row = idx >> 5, cc = idx & 31;
            short8 vv = *(const short8*)&Ct[row * 264 + cc * 8];
            *(short8*)&hrow[(size_t)row * H1_ + cc * 8] = vv;
        }
        __syncthreads();
    }
}

// ---------------- fused layer2 + gated combine: ring-3, depth-1 prefetch ----------------
// 64 rows x full H2=128 per block, grid B/64 = 256, 512 threads, 76 KB -> 2 blocks/CU.
// Chunk = K=64 slice of one expert; 32 chunks. Per chunk cid:
//   [stage(cid+1) -> slot (cid+1)%3] [vmcnt(3)] [s_barrier] [compute slot cid%3]
// RACE-FREE (rule R >= D+2 with R=3, D=1): writes at cid hit the slot read at
// cid-2; every wave passed cid-1's head barrier only after finishing cid-2's
// reads, and the issue at cid is after that barrier in program order.
__global__ __launch_bounds__(512, 4)
void fused_l2_combine_kernel(const unsigned short* __restrict__ h,
                             const unsigned short* __restrict__ w2t,
                             const float* __restrict__ b2,
                             const float* __restrict__ gates,
                             float* __restrict__ out) {
    __shared__ __align__(16) unsigned short ring[36864];   // 72 KB: A[3][4096] | B[3][8192]
    __shared__ float gL[16][64];                           //  4 KB

    unsigned short* Aslot = ring;            // slot s at s*4096 (64 rows x 64 k)
    unsigned short* Bslot = ring + 12288;    // slot s at s*8192 (128 n x 64 k)

    int b0 = blockIdx.x * 64;
    int t = threadIdx.x, w = t >> 6, lane = t & 63;
    int col = lane & 15, quad = lane >> 4;
    int wm = (w & 1) * 32, wn = (w >> 1) * 32;   // wn in {0,32,64,96}

    if (t < 256) {   // stage gates; first read (expert-0 epilogue) is past several barriers
        int te = t >> 4, r4 = (t & 15) * 4;
        *(float4_t*)&gL[te][r4] = *(const float4_t*)&gates[(size_t)te * B_ + b0 + r4];
    }

    int rowA = t >> 3;                               // 0..63
    int csw  = ((t & 7) ^ (rowA & 7)) * 8;           // pre-swizzled source chunk
    int ldsw = w * 512;

    float4_t tw0[2][2], tw1[2][2];
#pragma unroll
    for (int mi = 0; mi < 2; ++mi)
#pragma unroll
        for (int ni = 0; ni < 2; ++ni) {
            tw0[mi][ni] = (float4_t){0.f, 0.f, 0.f, 0.f};
            tw1[mi][ni] = (float4_t){0.f, 0.f, 0.f, 0.f};
        }

    // stage chunk cid (expert cid>>2, K-slice cid&3) into ring slot (3 loads/thread)
    auto stage = [&](int cid, int slot) {
        int ee = cid >> 2, kc = cid & 3;
        const unsigned short* hE = h + ((size_t)ee * B_ + b0 + rowA) * H1_ + kc * 64 + csw;
        async_copy16(hE, Aslot + slot * 4096 + ldsw);
        const unsigned short* wE = w2t + ((size_t)ee * H2_ + rowA) * H1_ + kc * 64 + csw;
        async_copy16(wE, Bslot + slot * 8192 + ldsw);
        async_copy16(wE + (size_t)64 * H1_, Bslot + slot * 8192 + 4096 + ldsw);
    };

    stage(0, 0);

    float4_t acc[2][2];
    int rd = 0, wr = 1;
#pragma unroll 1
    for (int cid = 0; cid < 32; ++cid) {
        if (cid < 31) {
            stage(cid + 1, wr);
            asm volatile("s_waitcnt vmcnt(3)" ::: "memory");   // cid's 3 landed; 3 in flight
        } else {
            asm volatile("s_waitcnt vmcnt(0)" ::: "memory");   // final drain
        }
        asm volatile("s_barrier" ::: "memory");

        if ((cid & 3) == 0) {
#pragma unroll
            for (int mi = 0; mi < 2; ++mi)
#pragma unroll
                for (int ni = 0; ni < 2; ++ni)
                    acc[mi][ni] = (float4_t){0.f, 0.f, 0.f, 0.f};
        }
        const unsigned short* Ac = Aslot + rd * 4096;
        const unsigned short* Bc = Bslot + rd * 8192;
#pragma unroll
        for (int kq = 0; kq < 2; ++kq) {
            int q = kq * 4 + quad;          // 0..7
            short8 af[2], bfv[2];
#pragma unroll
            for (int mi = 0; mi < 2; ++mi) {
                int r = wm + mi * 16 + col;
                af[mi] = *(const short8*)&Ac[r * 64 + ((q ^ (r & 7)) << 3)];
            }
#pragma unroll
            for (int ni = 0; ni < 2; ++ni) {
                int n = wn + ni * 16 + col;
                bfv[ni] = *(const short8*)&Bc[n * 64 + ((q ^ (n & 7)) << 3)];
            }
            __builtin_amdgcn_s_setprio(1);
#pragma unroll
            for (int mi = 0; mi < 2; ++mi)
#pragma unroll
                for (int ni = 0; ni < 2; ++ni)
                    acc[mi][ni] = __builtin_amdgcn_mfma_f32_16x16x32_bf16(
                        af[mi], bfv[ni], acc[mi][ni], 0, 0, 0);
            __builtin_amdgcn_s_setprio(0);
        }

        if ((cid & 3) == 3) {   // expert epilogue: bias + relu + gated accumulate
            int ee = cid >> 2;
#pragma unroll
            for (int ni = 0; ni < 2; ++ni) {
                float bv = b2[ee * H2_ + wn + ni * 16 + col];
#pragma unroll
                for (int mi = 0; mi < 2; ++mi) {
#pragma unroll
                    for (int p = 0; p < 4; ++p) {
                        int rloc = wm + mi * 16 + quad * 4 + p;
                        float v = acc[mi][ni][p] + bv;
                        v = v > 0.f ? v : 0.f;
                        tw0[mi][ni][p] += gL[ee][rloc] * v;
                        tw1[mi][ni][p] += gL[8 + ee][rloc] * v;
                    }
                }
            }
        }
        rd = (rd == 2) ? 0 : rd + 1;
        wr = (wr == 2) ? 0 : wr + 1;
    }

    // write out [T][B][H2]
#pragma unroll
    for (int mi = 0; mi < 2; ++mi) {
#pragma unroll
        for (int ni = 0; ni < 2; ++ni) {
            int n = wn + ni * 16 + col;
#pragma unroll
            for (int p = 0; p < 4; ++p) {
                int r = b0 + wm + mi * 16 + quad * 4 + p;
                out[(size_t)r * H2_ + n] = tw0[mi][ni][p];
                out[(size_t)B_ * H2_ + (size_t)r * H2_ + n] = tw1[mi][ni][p];
            }
        }
    }
}

extern "C" void kernel_launch(void* const* d_in, const int* in_sizes, int n_in,
                              void* d_out, int out_size, void* d_ws, size_t ws_size,
                              hipStream_t stream) {
    const float* x  = (const float*)d_in[0];
    const float* W1 = (const float*)d_in[1];
    const float* b1 = (const float*)d_in[2];
    const float* W2 = (const float*)d_in[3];
    const float* b2 = (const float*)d_in[4];
    const float* Wg = (const float*)d_in[5];
    const float* bg = (const float*)d_in[6];
    float* out = (float*)d_out;

    char* ws = (char*)d_ws;
    unsigned short* xb    = (unsigned short*)(ws);                // 16,777,216 B
    unsigned short* w1t   = (unsigned short*)(ws + 16777216);     //  2,097,152 B
    unsigned short* w2t   = (unsigned short*)(ws + 18874368);     //    524,288 B
    float*          gates = (float*)(ws + 19398656);              //  1,048,576 B  [16][B]
    unsigned short* h     = (unsigned short*)(ws + 20447232);     // 67,108,864 B
    // total: 87,556,096 B

    // dispatch 1: all prep + gates (x->bf16, W1^T, W2^T, gate softmax)
    prep_gates_kernel<<<dim3(2304), 256, 0, stream>>>(x, xb, W1, w1t, W2, w2t, Wg, bg, gates);

    // dispatch 2: layer 1 grouped GEMM, 256^2 tile, issue-at-head counted-vmcnt pipeline
    l1_gemm_kernel<<<dim3(512), 512, 0, stream>>>(xb, w1t, b1, h);

    // dispatch 3: fused layer 2 + gated combine, ring-3 depth-1, 2 blocks/CU
    fused_l2_combine_kernel<<<dim3(B_ / 64), 512, 0, stream>>>(h, w2t, b2, gates, out);
}